// Round 1
// baseline (403.395 us; speedup 1.0000x reference)
//
#include <hip/hip_runtime.h>
#include <math.h>

namespace {

constexpr int Bn = 4, Cn = 96, Hn = 64, Wn = 64, Ln = 4096, Din = 192;
constexpr int Kn = 4, Rn = 6, Dmlp = 384;
constexpr int NCH = 32, CLEN = 128;   // 32 chunks * 128 = L

__device__ __forceinline__ float softplusf_(float x) {
  return fmaxf(x, 0.f) + log1pf(expf(-fabsf(x)));
}
__device__ __forceinline__ float siluf_(float x) { return x / (1.f + expf(-x)); }
__device__ __forceinline__ float geluf_(float x) {
  return 0.5f * x * (1.f + erff(x * 0.7071067811865476f));
}

// ---------------------------------------------------------------------------
// K1: LayerNorm(96) + in_proj (96->192). 64 pixels/block, 256 threads.
// Output ucp in (B, Din, H*W) channel-planar layout (coalesced, conv-friendly).
// ---------------------------------------------------------------------------
__global__ __launch_bounds__(256) void k1_ln_inproj(
    const float* __restrict__ x, const float* __restrict__ gam,
    const float* __restrict__ bet, const float* __restrict__ W,
    float* __restrict__ ucp) {
  __shared__ float sx[64 * 97];
  const int tid = threadIdx.x;
  const int p0 = blockIdx.x * 64;
  const int b = p0 >> 12, pl0 = p0 & (Ln - 1);

  // load x tile [pp][c] (coalesced: pp fast)
  for (int f = tid; f < 64 * 96; f += 256) {
    int c = f >> 6, pp = f & 63;
    sx[pp * 97 + c] = x[((size_t)b * Cn + c) * Ln + pl0 + pp];
  }
  __syncthreads();
  if (tid < 64) {
    float m = 0.f;
    for (int c = 0; c < 96; ++c) m += sx[tid * 97 + c];
    m *= (1.f / 96.f);
    float v = 0.f;
    for (int c = 0; c < 96; ++c) { float t = sx[tid * 97 + c] - m; v += t * t; }
    v *= (1.f / 96.f);
    float rs = rsqrtf(v + 1e-5f);
    for (int c = 0; c < 96; ++c)
      sx[tid * 97 + c] = (sx[tid * 97 + c] - m) * rs * gam[c] + bet[c];
  }
  __syncthreads();

  // GEMM 64px x 192j: thread (g,q): g=tid&15 -> 4 pixels, q=tid>>4 -> 12 j's
  const int g = tid & 15, q = tid >> 4;
  float acc[4][12];
#pragma unroll
  for (int i = 0; i < 4; ++i)
#pragma unroll
    for (int j = 0; j < 12; ++j) acc[i][j] = 0.f;

  for (int c = 0; c < 96; ++c) {
    float xv[4];
#pragma unroll
    for (int i = 0; i < 4; ++i) xv[i] = sx[(4 * g + i) * 97 + c];
#pragma unroll
    for (int j = 0; j < 12; ++j) {
      float wv = W[(q * 12 + j) * 96 + c];
#pragma unroll
      for (int i = 0; i < 4; ++i) acc[i][j] = fmaf(xv[i], wv, acc[i][j]);
    }
  }
#pragma unroll
  for (int j = 0; j < 12; ++j) {
    int jj = q * 12 + j;
    float4 v = make_float4(acc[0][j], acc[1][j], acc[2][j], acc[3][j]);
    *reinterpret_cast<float4*>(
        &ucp[((size_t)b * Din + jj) * Ln + pl0 + 4 * g]) = v;
  }
}

// ---------------------------------------------------------------------------
// K2: depthwise 3x3 conv (SAME, zero pad) + SiLU -> ut (B, L, Din) pixel-major
//     + fused x_proj: dblp[b, p, k, c] (c=0..7) = sum_d u[p,d]*xw[k,c,d].
// One block per (b, h) row: 64 pixels; 256 threads = 4 waves x 48 channels.
// ---------------------------------------------------------------------------
__global__ __launch_bounds__(256) void k2_conv_proj(
    const float* __restrict__ ucp, const float* __restrict__ cw,
    const float* __restrict__ xw, float* __restrict__ ut,
    float* __restrict__ dblp) {
  __shared__ float su[64 * 193];
  const int tid = threadIdx.x;
  const int bh = blockIdx.x;
  const int b = bh >> 6, h = bh & 63;
  const int w = tid & 63, wg = tid >> 6;

  for (int dd = 0; dd < 48; ++dd) {
    int d = wg * 48 + dd;
    const float* base = &ucp[((size_t)b * Din + d) * Ln];
    float r0 = (h > 0) ? base[(h - 1) * 64 + w] : 0.f;
    float r1 = base[h * 64 + w];
    float r2 = (h < 63) ? base[(h + 1) * 64 + w] : 0.f;
    const float* wt = &cw[d * 9];
    float rl, rr, acc;
    rl = __shfl(r0, (w + 63) & 63); if (w == 0) rl = 0.f;
    rr = __shfl(r0, (w + 1) & 63);  if (w == 63) rr = 0.f;
    acc = rl * wt[0] + r0 * wt[1] + rr * wt[2];
    rl = __shfl(r1, (w + 63) & 63); if (w == 0) rl = 0.f;
    rr = __shfl(r1, (w + 1) & 63);  if (w == 63) rr = 0.f;
    acc += rl * wt[3] + r1 * wt[4] + rr * wt[5];
    rl = __shfl(r2, (w + 63) & 63); if (w == 0) rl = 0.f;
    rr = __shfl(r2, (w + 1) & 63);  if (w == 63) rr = 0.f;
    acc += rl * wt[6] + r2 * wt[7] + rr * wt[8];
    su[w * 193 + d] = siluf_(acc);
  }
  __syncthreads();

  // write ut (pixel-major, coalesced)
  for (int f = tid; f < 64 * Din; f += 256) {
    int pp = f / Din, d = f % Din;
    ut[((size_t)b * Ln + h * 64 + pp) * Din + d] = su[pp * 193 + d];
  }

  // x_proj: thread -> pixel w2 = tid>>2, direction k = tid&3 (8 outputs)
  const int w2 = tid >> 2, k = tid & 3;
  float a8[8];
#pragma unroll
  for (int j = 0; j < 8; ++j) a8[j] = 0.f;
  for (int d = 0; d < Din; ++d) {
    float uv = su[w2 * 193 + d];
#pragma unroll
    for (int j = 0; j < 8; ++j)
      a8[j] = fmaf(uv, xw[(k * 8 + j) * Din + d], a8[j]);
  }
  size_t off = ((size_t)b * Ln + h * 64 + w2) * 32 + k * 8;
#pragma unroll
  for (int j = 0; j < 8; ++j) dblp[off + j] = a8[j];
}

// ---------------------------------------------------------------------------
// Scan helpers: pixel index for scan position l in direction k
// ---------------------------------------------------------------------------
__device__ __forceinline__ int scan_pixel(int k, int l) {
  if (k == 0) return l;
  if (k == 1) return ((l & 63) << 6) | (l >> 6);
  if (k == 2) return Ln - 1 - l;
  int m2 = Ln - 1 - l;
  return ((m2 & 63) << 6) | (m2 >> 6);
}

// ---------------------------------------------------------------------------
// K4: scan pass 1 — per (b,k,chunk): (prod a, local h_end) per channel d.
// grid = B*K*NCH blocks x 192 threads.
// ---------------------------------------------------------------------------
__global__ __launch_bounds__(192) void k4_scan1(
    const float* __restrict__ ut, const float* __restrict__ dblp,
    const float* __restrict__ wdtg, const float* __restrict__ bdtg,
    const float* __restrict__ alog, float* __restrict__ apb,
    float* __restrict__ heb) {
  const int bid = blockIdx.x;
  const int ch = bid & (NCH - 1);
  const int bk = bid / NCH;
  const int b = bk >> 2, k = bk & 3;
  const int d = threadIdx.x;

  float wdt[6];
#pragma unroll
  for (int r = 0; r < 6; ++r) wdt[r] = wdtg[(k * Din + d) * 6 + r];
  const float bdt = bdtg[k * Din + d];
  const float Av = -expf(alog[k * Din + d]);

  const float* utb = &ut[(size_t)b * Ln * Din];
  const float* dbb = &dblp[(size_t)b * Ln * 32 + k * 8];

  float h = 0.f, ap = 1.f;
  for (int i = 0; i < CLEN; ++i) {
    int l = ch * CLEN + i;
    int p = scan_pixel(k, l);
    const float* dl = &dbb[(size_t)p * 32];
    float4 q0 = *reinterpret_cast<const float4*>(dl);
    float4 q1 = *reinterpret_cast<const float4*>(dl + 4);
    float xdt = bdt;
    xdt = fmaf(q0.x, wdt[0], xdt); xdt = fmaf(q0.y, wdt[1], xdt);
    xdt = fmaf(q0.z, wdt[2], xdt); xdt = fmaf(q0.w, wdt[3], xdt);
    xdt = fmaf(q1.x, wdt[4], xdt); xdt = fmaf(q1.y, wdt[5], xdt);
    float dt = softplusf_(xdt);
    float bs = q1.z;
    float u = utb[(size_t)p * Din + d];
    float a = expf(dt * Av);
    float bbv = dt * bs * u;
    h = fmaf(a, h, bbv);
    ap *= a;
  }
  size_t o = ((size_t)bk * NCH + ch) * Din + d;
  apb[o] = ap;
  heb[o] = h;
}

// ---------------------------------------------------------------------------
// K5: scan pass 2 — combine chunk carries. 3072 sequences x 32 chunks.
// ---------------------------------------------------------------------------
__global__ __launch_bounds__(256) void k5_carry(
    const float* __restrict__ apb, const float* __restrict__ heb,
    float* __restrict__ cin) {
  int t = blockIdx.x * 256 + threadIdx.x;
  if (t >= Bn * Kn * Din) return;
  int bk = t / Din, d = t % Din;
  float c = 0.f;
  for (int ch = 0; ch < NCH; ++ch) {
    size_t o = ((size_t)bk * NCH + ch) * Din + d;
    cin[o] = c;
    c = fmaf(apb[o], c, heb[o]);
  }
}

// ---------------------------------------------------------------------------
// K6: scan pass 3 — recompute recurrence with carry-in, y = h*Cs + D*u,
// atomically accumulate into yacc (pixel-order, all 4 directions merge here).
// ---------------------------------------------------------------------------
__global__ __launch_bounds__(192) void k6_scan2(
    const float* __restrict__ ut, const float* __restrict__ dblp,
    const float* __restrict__ wdtg, const float* __restrict__ bdtg,
    const float* __restrict__ alog, const float* __restrict__ dsg,
    const float* __restrict__ cin, float* __restrict__ yacc) {
  const int bid = blockIdx.x;
  const int ch = bid & (NCH - 1);
  const int bk = bid / NCH;
  const int b = bk >> 2, k = bk & 3;
  const int d = threadIdx.x;

  float wdt[6];
#pragma unroll
  for (int r = 0; r < 6; ++r) wdt[r] = wdtg[(k * Din + d) * 6 + r];
  const float bdt = bdtg[k * Din + d];
  const float Av = -expf(alog[k * Din + d]);
  const float Dv = dsg[k * Din + d];

  const float* utb = &ut[(size_t)b * Ln * Din];
  const float* dbb = &dblp[(size_t)b * Ln * 32 + k * 8];
  float* yb = &yacc[(size_t)b * Ln * Din];

  float h = cin[((size_t)bk * NCH + ch) * Din + d];
  for (int i = 0; i < CLEN; ++i) {
    int l = ch * CLEN + i;
    int p = scan_pixel(k, l);
    const float* dl = &dbb[(size_t)p * 32];
    float4 q0 = *reinterpret_cast<const float4*>(dl);
    float4 q1 = *reinterpret_cast<const float4*>(dl + 4);
    float xdt = bdt;
    xdt = fmaf(q0.x, wdt[0], xdt); xdt = fmaf(q0.y, wdt[1], xdt);
    xdt = fmaf(q0.z, wdt[2], xdt); xdt = fmaf(q0.w, wdt[3], xdt);
    xdt = fmaf(q1.x, wdt[4], xdt); xdt = fmaf(q1.y, wdt[5], xdt);
    float dt = softplusf_(xdt);
    float bs = q1.z, cs = q1.w;
    float u = utb[(size_t)p * Din + d];
    float a = expf(dt * Av);
    float bbv = dt * bs * u;
    h = fmaf(a, h, bbv);
    float y = h * cs + Dv * u;
    atomicAdd(&yb[(size_t)p * Din + d], y);
  }
}

// ---------------------------------------------------------------------------
// K7: out_norm LN(192) + out_proj (192->96) + residual with transpose(x)
//     -> zt (B, L, 96). 64 pixels/block, 256 threads.
// ---------------------------------------------------------------------------
__global__ __launch_bounds__(256) void k7_outproj(
    const float* __restrict__ yacc, const float* __restrict__ gam,
    const float* __restrict__ bet, const float* __restrict__ W,
    const float* __restrict__ x, float* __restrict__ zt) {
  __shared__ float sy[64 * 193];
  const int tid = threadIdx.x;
  const int p0 = blockIdx.x * 64;
  const int b = p0 >> 12, pl0 = p0 & (Ln - 1);

  for (int f = tid; f < 64 * Din; f += 256) {
    int pp = f / Din, d = f % Din;
    sy[pp * 193 + d] = yacc[((size_t)p0 + pp) * Din + d];
  }
  __syncthreads();
  if (tid < 64) {
    float m = 0.f;
    for (int d2 = 0; d2 < Din; ++d2) m += sy[tid * 193 + d2];
    m *= (1.f / 192.f);
    float v = 0.f;
    for (int d2 = 0; d2 < Din; ++d2) { float t = sy[tid * 193 + d2] - m; v += t * t; }
    v *= (1.f / 192.f);
    float rs = rsqrtf(v + 1e-5f);
    for (int d2 = 0; d2 < Din; ++d2)
      sy[tid * 193 + d2] = (sy[tid * 193 + d2] - m) * rs * gam[d2] + bet[d2];
  }
  __syncthreads();

  const int g = tid & 15, q = tid >> 4;  // 4 px, 6 c's
  float acc[4][6];
#pragma unroll
  for (int i = 0; i < 4; ++i)
#pragma unroll
    for (int j = 0; j < 6; ++j) acc[i][j] = 0.f;

  for (int d2 = 0; d2 < Din; ++d2) {
    float yv[4];
#pragma unroll
    for (int i = 0; i < 4; ++i) yv[i] = sy[(4 * g + i) * 193 + d2];
#pragma unroll
    for (int j = 0; j < 6; ++j) {
      float wv = W[(q * 6 + j) * Din + d2];
#pragma unroll
      for (int i = 0; i < 4; ++i) acc[i][j] = fmaf(yv[i], wv, acc[i][j]);
    }
  }
  __syncthreads();            // done reading sy; reuse its space for z-staging
  float* sz = sy;             // [64][97]
#pragma unroll
  for (int j = 0; j < 6; ++j)
#pragma unroll
    for (int i = 0; i < 4; ++i) sz[(4 * g + i) * 97 + q * 6 + j] = acc[i][j];
  __syncthreads();

  for (int f = tid; f < 64 * 96; f += 256) {
    int pp = f / 96, c = f % 96;
    zt[((size_t)p0 + pp) * 96 + c] =
        sz[pp * 97 + c] + x[((size_t)b * Cn + c) * Ln + pl0 + pp];
  }
}

// ---------------------------------------------------------------------------
// K8: MLP — LN(96) + fc1(96->384) + gelu + fc2(384->96) + residuals,
// final output in (B, C, H, W). 32 pixels/block, 256 threads.
// ---------------------------------------------------------------------------
__global__ __launch_bounds__(256) void k8_mlp(
    const float* __restrict__ zt, const float* __restrict__ g2,
    const float* __restrict__ b2, const float* __restrict__ w1,
    const float* __restrict__ b1f, const float* __restrict__ w2,
    const float* __restrict__ b2f, const float* __restrict__ x,
    float* __restrict__ out) {
  __shared__ float smn[32 * 101];   // reused as sm (MLP out) after fc1
  __shared__ float sh[32 * 385];
  const int tid = threadIdx.x;
  const int p0 = blockIdx.x * 32;
  const int b = p0 >> 12, pl0 = p0 & (Ln - 1);

  for (int f = tid; f < 32 * 96; f += 256) {
    int pp = f / 96, c = f % 96;
    smn[pp * 101 + c] = zt[((size_t)p0 + pp) * 96 + c];
  }
  __syncthreads();
  if (tid < 32) {
    float m = 0.f;
    for (int c = 0; c < 96; ++c) m += smn[tid * 101 + c];
    m *= (1.f / 96.f);
    float v = 0.f;
    for (int c = 0; c < 96; ++c) { float t = smn[tid * 101 + c] - m; v += t * t; }
    v *= (1.f / 96.f);
    float rs = rsqrtf(v + 1e-5f);
    for (int c = 0; c < 96; ++c)
      smn[tid * 101 + c] = (smn[tid * 101 + c] - m) * rs * g2[c] + b2[c];
  }
  __syncthreads();

  // fc1 + gelu: thread (g8 = tid&7 -> 4 px, q = tid>>3 -> 12 j's of 384)
  const int g8 = tid & 7, q = tid >> 3;
  {
    float acc[4][12];
#pragma unroll
    for (int i = 0; i < 4; ++i)
#pragma unroll
      for (int j = 0; j < 12; ++j) acc[i][j] = 0.f;
    for (int c = 0; c < 96; ++c) {
      float mv[4];
#pragma unroll
      for (int i = 0; i < 4; ++i) mv[i] = smn[(4 * g8 + i) * 101 + c];
#pragma unroll
      for (int j = 0; j < 12; ++j) {
        float wv = w1[(q * 12 + j) * 96 + c];
#pragma unroll
        for (int i = 0; i < 4; ++i) acc[i][j] = fmaf(mv[i], wv, acc[i][j]);
      }
    }
#pragma unroll
    for (int j = 0; j < 12; ++j) {
      int jj = q * 12 + j;
      float bj = b1f[jj];
#pragma unroll
      for (int i = 0; i < 4; ++i)
        sh[(4 * g8 + i) * 385 + jj] = geluf_(acc[i][j] + bj);
    }
  }
  __syncthreads();

  // fc2: thread (g8, q) -> 4 px x 3 c's
  {
    float a2[4][3];
#pragma unroll
    for (int i = 0; i < 4; ++i)
#pragma unroll
      for (int j = 0; j < 3; ++j) a2[i][j] = 0.f;
    for (int j = 0; j < 384; ++j) {
      float hv[4];
#pragma unroll
      for (int i = 0; i < 4; ++i) hv[i] = sh[(4 * g8 + i) * 385 + j];
#pragma unroll
      for (int cc = 0; cc < 3; ++cc) {
        float wv = w2[(q * 3 + cc) * 384 + j];
#pragma unroll
        for (int i = 0; i < 4; ++i) a2[i][cc] = fmaf(hv[i], wv, a2[i][cc]);
      }
    }
    float* sm = smn;  // reuse (all smn reads completed before prior barrier)
#pragma unroll
    for (int cc = 0; cc < 3; ++cc)
#pragma unroll
      for (int i = 0; i < 4; ++i)
        sm[(4 * g8 + i) * 101 + q * 3 + cc] = a2[i][cc] + b2f[q * 3 + cc];
  }
  __syncthreads();

  // out[b,c,p] = x[b,c,p] + zt[p,c] + m[p,c]   (coalesced over pp)
  for (int f = tid; f < 32 * 96; f += 256) {
    int c = f >> 5, pp = f & 31;
    size_t xi = ((size_t)b * Cn + c) * Ln + pl0 + pp;
    out[xi] = x[xi] + zt[((size_t)p0 + pp) * 96 + c] + smn[pp * 101 + c];
  }
}

}  // namespace

extern "C" void kernel_launch(void* const* d_in, const int* in_sizes, int n_in,
                              void* d_out, int out_size, void* d_ws,
                              size_t ws_size, hipStream_t stream) {
  const float* x        = (const float*)d_in[0];
  const float* norm1_g  = (const float*)d_in[1];
  const float* norm1_b  = (const float*)d_in[2];
  const float* in_proj  = (const float*)d_in[3];
  const float* conv_w   = (const float*)d_in[4];
  const float* x_proj   = (const float*)d_in[5];
  const float* dt_w     = (const float*)d_in[6];
  const float* dt_b     = (const float*)d_in[7];
  const float* A_logs   = (const float*)d_in[8];
  const float* Ds       = (const float*)d_in[9];
  const float* onorm_g  = (const float*)d_in[10];
  const float* onorm_b  = (const float*)d_in[11];
  const float* out_proj = (const float*)d_in[12];
  const float* norm2_g  = (const float*)d_in[13];
  const float* norm2_b  = (const float*)d_in[14];
  const float* fc1_w    = (const float*)d_in[15];
  const float* fc1_b    = (const float*)d_in[16];
  const float* fc2_w    = (const float*)d_in[17];
  const float* fc2_b    = (const float*)d_in[18];
  float* out = (float*)d_out;

  // workspace layout (floats)
  float* ws = (float*)d_ws;
  size_t o = 0;
  float* ucp  = ws + o; o += (size_t)Bn * Din * Ln;          // 3,145,728
  float* ut   = ws + o; o += (size_t)Bn * Ln * Din;          // 3,145,728
  float* dblp = ws + o; o += (size_t)Bn * Ln * 32;           //   524,288
  float* apb  = ws + o; o += (size_t)Bn * Kn * NCH * Din;    //    98,304
  float* heb  = ws + o; o += (size_t)Bn * Kn * NCH * Din;    //    98,304
  float* cin  = ws + o; o += (size_t)Bn * Kn * NCH * Din;    //    98,304
  float* yacc = ws + o; o += (size_t)Bn * Ln * Din;          // 3,145,728
  float* zt   = ws + o; o += (size_t)Bn * Ln * Cn;           // 1,572,864

  hipMemsetAsync(yacc, 0, (size_t)Bn * Ln * Din * sizeof(float), stream);

  k1_ln_inproj<<<256, 256, 0, stream>>>(x, norm1_g, norm1_b, in_proj, ucp);
  k2_conv_proj<<<Bn * Hn, 256, 0, stream>>>(ucp, conv_w, x_proj, ut, dblp);
  k4_scan1<<<Bn * Kn * NCH, 192, 0, stream>>>(ut, dblp, dt_w, dt_b, A_logs,
                                              apb, heb);
  k5_carry<<<12, 256, 0, stream>>>(apb, heb, cin);
  k6_scan2<<<Bn * Kn * NCH, 192, 0, stream>>>(ut, dblp, dt_w, dt_b, A_logs, Ds,
                                              cin, yacc);
  k7_outproj<<<256, 256, 0, stream>>>(yacc, onorm_g, onorm_b, out_proj, x, zt);
  k8_mlp<<<512, 256, 0, stream>>>(zt, norm2_g, norm2_b, fc1_w, fc1_b, fc2_w,
                                  fc2_b, x, out);
}

// Round 2
// 326.830 us; speedup vs baseline: 1.2343x; 1.2343x over previous
//
#include <hip/hip_runtime.h>
#include <math.h>

namespace {

constexpr int Bn = 4, Cn = 96, Hn = 64, Wn = 64, Ln = 4096, Din = 192;
constexpr int Kn = 4, Rn = 6, Dmlp = 384;
constexpr int NCH = 128, CLEN = 32;   // 128 chunks * 32 = L  (occupancy: 2048 blocks)

__device__ __forceinline__ float softplusf_(float x) {
  return fmaxf(x, 0.f) + log1pf(expf(-fabsf(x)));
}
__device__ __forceinline__ float siluf_(float x) { return x / (1.f + expf(-x)); }
__device__ __forceinline__ float geluf_(float x) {
  return 0.5f * x * (1.f + erff(x * 0.7071067811865476f));
}

// ---------------------------------------------------------------------------
// K1: LayerNorm(96) + in_proj (96->192). 64 pixels/block, 256 threads.
// LN parallelized 4 lanes/pixel + shfl_xor combine.
// ---------------------------------------------------------------------------
__global__ __launch_bounds__(256) void k1_ln_inproj(
    const float* __restrict__ x, const float* __restrict__ gam,
    const float* __restrict__ bet, const float* __restrict__ W,
    float* __restrict__ ucp) {
  __shared__ float sx[64 * 97];
  const int tid = threadIdx.x;
  const int p0 = blockIdx.x * 64;
  const int b = p0 >> 12, pl0 = p0 & (Ln - 1);

  for (int f = tid; f < 64 * 96; f += 256) {
    int c = f >> 6, pp = f & 63;
    sx[pp * 97 + c] = x[((size_t)b * Cn + c) * Ln + pl0 + pp];
  }
  __syncthreads();
  {
    const int pp = tid >> 2, t4 = tid & 3;   // 4 lanes per pixel, 24 ch each
    float s = 0.f;
    for (int c = t4 * 24; c < t4 * 24 + 24; ++c) s += sx[pp * 97 + c];
    s += __shfl_xor(s, 1, 4); s += __shfl_xor(s, 2, 4);
    float m = s * (1.f / 96.f);
    float v = 0.f;
    for (int c = t4 * 24; c < t4 * 24 + 24; ++c) {
      float t = sx[pp * 97 + c] - m; v += t * t;
    }
    v += __shfl_xor(v, 1, 4); v += __shfl_xor(v, 2, 4);
    float rs = rsqrtf(v * (1.f / 96.f) + 1e-5f);
    for (int c = t4 * 24; c < t4 * 24 + 24; ++c)
      sx[pp * 97 + c] = (sx[pp * 97 + c] - m) * rs * gam[c] + bet[c];
  }
  __syncthreads();

  const int g = tid & 15, q = tid >> 4;   // 4 px x 12 j
  float acc[4][12];
#pragma unroll
  for (int i = 0; i < 4; ++i)
#pragma unroll
    for (int j = 0; j < 12; ++j) acc[i][j] = 0.f;

  for (int c = 0; c < 96; ++c) {
    float xv[4];
#pragma unroll
    for (int i = 0; i < 4; ++i) xv[i] = sx[(4 * g + i) * 97 + c];
#pragma unroll
    for (int j = 0; j < 12; ++j) {
      float wv = W[(q * 12 + j) * 96 + c];
#pragma unroll
      for (int i = 0; i < 4; ++i) acc[i][j] = fmaf(xv[i], wv, acc[i][j]);
    }
  }
#pragma unroll
  for (int j = 0; j < 12; ++j) {
    int jj = q * 12 + j;
    float4 v = make_float4(acc[0][j], acc[1][j], acc[2][j], acc[3][j]);
    *reinterpret_cast<float4*>(
        &ucp[((size_t)b * Din + jj) * Ln + pl0 + 4 * g]) = v;
  }
}

// ---------------------------------------------------------------------------
// K2: depthwise 3x3 conv + SiLU -> ut (B,L,Din) pixel-major
//     + fused x_proj -> dblp (B,L,K,8)
// ---------------------------------------------------------------------------
__global__ __launch_bounds__(256) void k2_conv_proj(
    const float* __restrict__ ucp, const float* __restrict__ cw,
    const float* __restrict__ xw, float* __restrict__ ut,
    float* __restrict__ dblp) {
  __shared__ float su[64 * 193];
  const int tid = threadIdx.x;
  const int bh = blockIdx.x;
  const int b = bh >> 6, h = bh & 63;
  const int w = tid & 63, wg = tid >> 6;

  for (int dd = 0; dd < 48; ++dd) {
    int d = wg * 48 + dd;
    const float* base = &ucp[((size_t)b * Din + d) * Ln];
    float r0 = (h > 0) ? base[(h - 1) * 64 + w] : 0.f;
    float r1 = base[h * 64 + w];
    float r2 = (h < 63) ? base[(h + 1) * 64 + w] : 0.f;
    const float* wt = &cw[d * 9];
    float rl, rr, acc;
    rl = __shfl(r0, (w + 63) & 63); if (w == 0) rl = 0.f;
    rr = __shfl(r0, (w + 1) & 63);  if (w == 63) rr = 0.f;
    acc = rl * wt[0] + r0 * wt[1] + rr * wt[2];
    rl = __shfl(r1, (w + 63) & 63); if (w == 0) rl = 0.f;
    rr = __shfl(r1, (w + 1) & 63);  if (w == 63) rr = 0.f;
    acc += rl * wt[3] + r1 * wt[4] + rr * wt[5];
    rl = __shfl(r2, (w + 63) & 63); if (w == 0) rl = 0.f;
    rr = __shfl(r2, (w + 1) & 63);  if (w == 63) rr = 0.f;
    acc += rl * wt[6] + r2 * wt[7] + rr * wt[8];
    su[w * 193 + d] = siluf_(acc);
  }
  __syncthreads();

  for (int f = tid; f < 64 * Din; f += 256) {
    int pp = f / Din, d = f % Din;
    ut[((size_t)b * Ln + h * 64 + pp) * Din + d] = su[pp * 193 + d];
  }

  const int w2 = tid >> 2, k = tid & 3;
  float a8[8];
#pragma unroll
  for (int j = 0; j < 8; ++j) a8[j] = 0.f;
  for (int d = 0; d < Din; ++d) {
    float uv = su[w2 * 193 + d];
#pragma unroll
    for (int j = 0; j < 8; ++j)
      a8[j] = fmaf(uv, xw[(k * 8 + j) * Din + d], a8[j]);
  }
  size_t off = ((size_t)b * Ln + h * 64 + w2) * 32 + k * 8;
#pragma unroll
  for (int j = 0; j < 8; ++j) dblp[off + j] = a8[j];
}

__device__ __forceinline__ int scan_pixel(int k, int l) {
  if (k == 0) return l;
  if (k == 1) return ((l & 63) << 6) | (l >> 6);
  if (k == 2) return Ln - 1 - l;
  int m2 = Ln - 1 - l;
  return ((m2 & 63) << 6) | (m2 >> 6);
}

// ---------------------------------------------------------------------------
// K4: scan pass 1 — per (b,k,chunk): (prod a, local h_end) per channel d.
// ---------------------------------------------------------------------------
__global__ __launch_bounds__(192) void k4_scan1(
    const float* __restrict__ ut, const float* __restrict__ dblp,
    const float* __restrict__ wdtg, const float* __restrict__ bdtg,
    const float* __restrict__ alog, float* __restrict__ apb,
    float* __restrict__ heb) {
  const int bid = blockIdx.x;
  const int ch = bid & (NCH - 1);
  const int bk = bid / NCH;
  const int b = bk >> 2, k = bk & 3;
  const int d = threadIdx.x;

  float wdt[6];
#pragma unroll
  for (int r = 0; r < 6; ++r) wdt[r] = wdtg[(k * Din + d) * 6 + r];
  const float bdt = bdtg[k * Din + d];
  const float Av = -expf(alog[k * Din + d]);

  const float* utb = &ut[(size_t)b * Ln * Din];
  const float* dbb = &dblp[(size_t)b * Ln * 32 + k * 8];

  float h = 0.f, ap = 1.f;
  for (int i = 0; i < CLEN; ++i) {
    int l = ch * CLEN + i;
    int p = scan_pixel(k, l);
    const float* dl = &dbb[(size_t)p * 32];
    float4 q0 = *reinterpret_cast<const float4*>(dl);
    float4 q1 = *reinterpret_cast<const float4*>(dl + 4);
    float xdt = bdt;
    xdt = fmaf(q0.x, wdt[0], xdt); xdt = fmaf(q0.y, wdt[1], xdt);
    xdt = fmaf(q0.z, wdt[2], xdt); xdt = fmaf(q0.w, wdt[3], xdt);
    xdt = fmaf(q1.x, wdt[4], xdt); xdt = fmaf(q1.y, wdt[5], xdt);
    float dt = softplusf_(xdt);
    float bs = q1.z;
    float u = utb[(size_t)p * Din + d];
    float a = expf(dt * Av);
    float bbv = dt * bs * u;
    h = fmaf(a, h, bbv);
    ap *= a;
  }
  size_t o = ((size_t)bk * NCH + ch) * Din + d;
  apb[o] = ap;
  heb[o] = h;
}

// ---------------------------------------------------------------------------
// K5: scan pass 2 — combine chunk carries (3072 seqs x 128 chunks).
// ---------------------------------------------------------------------------
__global__ __launch_bounds__(256) void k5_carry(
    const float* __restrict__ apb, const float* __restrict__ heb,
    float* __restrict__ cin) {
  int t = blockIdx.x * 256 + threadIdx.x;
  if (t >= Bn * Kn * Din) return;
  int bk = t / Din, d = t % Din;
  float c = 0.f;
  for (int ch = 0; ch < NCH; ++ch) {
    size_t o = ((size_t)bk * NCH + ch) * Din + d;
    cin[o] = c;
    c = fmaf(apb[o], c, heb[o]);
  }
}

// ---------------------------------------------------------------------------
// K6: scan pass 3 — recurrence with carry-in, y accumulated via atomicAdd.
// ---------------------------------------------------------------------------
__global__ __launch_bounds__(192) void k6_scan2(
    const float* __restrict__ ut, const float* __restrict__ dblp,
    const float* __restrict__ wdtg, const float* __restrict__ bdtg,
    const float* __restrict__ alog, const float* __restrict__ dsg,
    const float* __restrict__ cin, float* __restrict__ yacc) {
  const int bid = blockIdx.x;
  const int ch = bid & (NCH - 1);
  const int bk = bid / NCH;
  const int b = bk >> 2, k = bk & 3;
  const int d = threadIdx.x;

  float wdt[6];
#pragma unroll
  for (int r = 0; r < 6; ++r) wdt[r] = wdtg[(k * Din + d) * 6 + r];
  const float bdt = bdtg[k * Din + d];
  const float Av = -expf(alog[k * Din + d]);
  const float Dv = dsg[k * Din + d];

  const float* utb = &ut[(size_t)b * Ln * Din];
  const float* dbb = &dblp[(size_t)b * Ln * 32 + k * 8];
  float* yb = &yacc[(size_t)b * Ln * Din];

  float h = cin[((size_t)bk * NCH + ch) * Din + d];
  for (int i = 0; i < CLEN; ++i) {
    int l = ch * CLEN + i;
    int p = scan_pixel(k, l);
    const float* dl = &dbb[(size_t)p * 32];
    float4 q0 = *reinterpret_cast<const float4*>(dl);
    float4 q1 = *reinterpret_cast<const float4*>(dl + 4);
    float xdt = bdt;
    xdt = fmaf(q0.x, wdt[0], xdt); xdt = fmaf(q0.y, wdt[1], xdt);
    xdt = fmaf(q0.z, wdt[2], xdt); xdt = fmaf(q0.w, wdt[3], xdt);
    xdt = fmaf(q1.x, wdt[4], xdt); xdt = fmaf(q1.y, wdt[5], xdt);
    float dt = softplusf_(xdt);
    float bs = q1.z, cs = q1.w;
    float u = utb[(size_t)p * Din + d];
    float a = expf(dt * Av);
    float bbv = dt * bs * u;
    h = fmaf(a, h, bbv);
    float y = h * cs + Dv * u;
    atomicAdd(&yb[(size_t)p * Din + d], y);
  }
}

// ---------------------------------------------------------------------------
// K7: out_norm LN(192) + out_proj (192->96) + residual -> zt (B,L,96).
// LN parallelized 4 lanes/pixel.
// ---------------------------------------------------------------------------
__global__ __launch_bounds__(256) void k7_outproj(
    const float* __restrict__ yacc, const float* __restrict__ gam,
    const float* __restrict__ bet, const float* __restrict__ W,
    const float* __restrict__ x, float* __restrict__ zt) {
  __shared__ float sy[64 * 193];
  const int tid = threadIdx.x;
  const int p0 = blockIdx.x * 64;
  const int b = p0 >> 12, pl0 = p0 & (Ln - 1);

  for (int f = tid; f < 64 * Din; f += 256) {
    int pp = f / Din, d = f % Din;
    sy[pp * 193 + d] = yacc[((size_t)p0 + pp) * Din + d];
  }
  __syncthreads();
  {
    const int pp = tid >> 2, t4 = tid & 3;   // 4 lanes/pixel, 48 ch each
    float s = 0.f;
    for (int d2 = t4 * 48; d2 < t4 * 48 + 48; ++d2) s += sy[pp * 193 + d2];
    s += __shfl_xor(s, 1, 4); s += __shfl_xor(s, 2, 4);
    float m = s * (1.f / 192.f);
    float v = 0.f;
    for (int d2 = t4 * 48; d2 < t4 * 48 + 48; ++d2) {
      float t = sy[pp * 193 + d2] - m; v += t * t;
    }
    v += __shfl_xor(v, 1, 4); v += __shfl_xor(v, 2, 4);
    float rs = rsqrtf(v * (1.f / 192.f) + 1e-5f);
    for (int d2 = t4 * 48; d2 < t4 * 48 + 48; ++d2)
      sy[pp * 193 + d2] = (sy[pp * 193 + d2] - m) * rs * gam[d2] + bet[d2];
  }
  __syncthreads();

  const int g = tid & 15, q = tid >> 4;  // 4 px x 6 c
  float acc[4][6];
#pragma unroll
  for (int i = 0; i < 4; ++i)
#pragma unroll
    for (int j = 0; j < 6; ++j) acc[i][j] = 0.f;

  for (int d2 = 0; d2 < Din; ++d2) {
    float yv[4];
#pragma unroll
    for (int i = 0; i < 4; ++i) yv[i] = sy[(4 * g + i) * 193 + d2];
#pragma unroll
    for (int j = 0; j < 6; ++j) {
      float wv = W[(q * 6 + j) * Din + d2];
#pragma unroll
      for (int i = 0; i < 4; ++i) acc[i][j] = fmaf(yv[i], wv, acc[i][j]);
    }
  }
  __syncthreads();
  float* sz = sy;   // reuse as [64][97]
#pragma unroll
  for (int j = 0; j < 6; ++j)
#pragma unroll
    for (int i = 0; i < 4; ++i) sz[(4 * g + i) * 97 + q * 6 + j] = acc[i][j];
  __syncthreads();

  for (int f = tid; f < 64 * 96; f += 256) {
    int pp = f / 96, c = f % 96;
    zt[((size_t)p0 + pp) * 96 + c] =
        sz[pp * 97 + c] + x[((size_t)b * Cn + c) * Ln + pl0 + pp];
  }
}

// ---------------------------------------------------------------------------
// K8: MLP — LN(96) + fc1 + gelu + fc2 + residuals -> out (B,C,H,W).
// LN parallelized 8 lanes/pixel.
// ---------------------------------------------------------------------------
__global__ __launch_bounds__(256) void k8_mlp(
    const float* __restrict__ zt, const float* __restrict__ g2,
    const float* __restrict__ b2, const float* __restrict__ w1,
    const float* __restrict__ b1f, const float* __restrict__ w2,
    const float* __restrict__ b2f, const float* __restrict__ x,
    float* __restrict__ out) {
  __shared__ float smn[32 * 101];
  __shared__ float sh[32 * 385];
  const int tid = threadIdx.x;
  const int p0 = blockIdx.x * 32;
  const int b = p0 >> 12, pl0 = p0 & (Ln - 1);

  for (int f = tid; f < 32 * 96; f += 256) {
    int pp = f / 96, c = f % 96;
    smn[pp * 101 + c] = zt[((size_t)p0 + pp) * 96 + c];
  }
  __syncthreads();
  {
    const int pp = tid >> 3, t8 = tid & 7;   // 8 lanes/pixel, 12 ch each
    float s = 0.f;
    for (int c = t8 * 12; c < t8 * 12 + 12; ++c) s += smn[pp * 101 + c];
    s += __shfl_xor(s, 1, 8); s += __shfl_xor(s, 2, 8); s += __shfl_xor(s, 4, 8);
    float m = s * (1.f / 96.f);
    float v = 0.f;
    for (int c = t8 * 12; c < t8 * 12 + 12; ++c) {
      float t = smn[pp * 101 + c] - m; v += t * t;
    }
    v += __shfl_xor(v, 1, 8); v += __shfl_xor(v, 2, 8); v += __shfl_xor(v, 4, 8);
    float rs = rsqrtf(v * (1.f / 96.f) + 1e-5f);
    for (int c = t8 * 12; c < t8 * 12 + 12; ++c)
      smn[pp * 101 + c] = (smn[pp * 101 + c] - m) * rs * g2[c] + b2[c];
  }
  __syncthreads();

  const int g8 = tid & 7, q = tid >> 3;
  {
    float acc[4][12];
#pragma unroll
    for (int i = 0; i < 4; ++i)
#pragma unroll
      for (int j = 0; j < 12; ++j) acc[i][j] = 0.f;
    for (int c = 0; c < 96; ++c) {
      float mv[4];
#pragma unroll
      for (int i = 0; i < 4; ++i) mv[i] = smn[(4 * g8 + i) * 101 + c];
#pragma unroll
      for (int j = 0; j < 12; ++j) {
        float wv = w1[(q * 12 + j) * 96 + c];
#pragma unroll
        for (int i = 0; i < 4; ++i) acc[i][j] = fmaf(mv[i], wv, acc[i][j]);
      }
    }
#pragma unroll
    for (int j = 0; j < 12; ++j) {
      int jj = q * 12 + j;
      float bj = b1f[jj];
#pragma unroll
      for (int i = 0; i < 4; ++i)
        sh[(4 * g8 + i) * 385 + jj] = geluf_(acc[i][j] + bj);
    }
  }
  __syncthreads();
  {
    float a2[4][3];
#pragma unroll
    for (int i = 0; i < 4; ++i)
#pragma unroll
      for (int j = 0; j < 3; ++j) a2[i][j] = 0.f;
    for (int j = 0; j < 384; ++j) {
      float hv[4];
#pragma unroll
      for (int i = 0; i < 4; ++i) hv[i] = sh[(4 * g8 + i) * 385 + j];
#pragma unroll
      for (int cc = 0; cc < 3; ++cc) {
        float wv = w2[(q * 3 + cc) * 384 + j];
#pragma unroll
        for (int i = 0; i < 4; ++i) a2[i][cc] = fmaf(hv[i], wv, a2[i][cc]);
      }
    }
    float* sm = smn;
#pragma unroll
    for (int cc = 0; cc < 3; ++cc)
#pragma unroll
      for (int i = 0; i < 4; ++i)
        sm[(4 * g8 + i) * 101 + q * 3 + cc] = a2[i][cc] + b2f[q * 3 + cc];
  }
  __syncthreads();

  for (int f = tid; f < 32 * 96; f += 256) {
    int c = f >> 5, pp = f & 31;
    size_t xi = ((size_t)b * Cn + c) * Ln + pl0 + pp;
    out[xi] = x[xi] + zt[((size_t)p0 + pp) * 96 + c] + smn[pp * 101 + c];
  }
}

}  // namespace

extern "C" void kernel_launch(void* const* d_in, const int* in_sizes, int n_in,
                              void* d_out, int out_size, void* d_ws,
                              size_t ws_size, hipStream_t stream) {
  const float* x        = (const float*)d_in[0];
  const float* norm1_g  = (const float*)d_in[1];
  const float* norm1_b  = (const float*)d_in[2];
  const float* in_proj  = (const float*)d_in[3];
  const float* conv_w   = (const float*)d_in[4];
  const float* x_proj   = (const float*)d_in[5];
  const float* dt_w     = (const float*)d_in[6];
  const float* dt_b     = (const float*)d_in[7];
  const float* A_logs   = (const float*)d_in[8];
  const float* Ds       = (const float*)d_in[9];
  const float* onorm_g  = (const float*)d_in[10];
  const float* onorm_b  = (const float*)d_in[11];
  const float* out_proj = (const float*)d_in[12];
  const float* norm2_g  = (const float*)d_in[13];
  const float* norm2_b  = (const float*)d_in[14];
  const float* fc1_w    = (const float*)d_in[15];
  const float* fc1_b    = (const float*)d_in[16];
  const float* fc2_w    = (const float*)d_in[17];
  const float* fc2_b    = (const float*)d_in[18];
  float* out = (float*)d_out;

  float* ws = (float*)d_ws;
  size_t o = 0;
  float* ucp  = ws + o; o += (size_t)Bn * Din * Ln;
  float* ut   = ws + o; o += (size_t)Bn * Ln * Din;
  float* dblp = ws + o; o += (size_t)Bn * Ln * 32;
  float* apb  = ws + o; o += (size_t)Bn * Kn * NCH * Din;
  float* heb  = ws + o; o += (size_t)Bn * Kn * NCH * Din;
  float* cin  = ws + o; o += (size_t)Bn * Kn * NCH * Din;
  float* yacc = ws + o; o += (size_t)Bn * Ln * Din;
  float* zt   = ws + o; o += (size_t)Bn * Ln * Cn;

  hipMemsetAsync(yacc, 0, (size_t)Bn * Ln * Din * sizeof(float), stream);

  k1_ln_inproj<<<256, 256, 0, stream>>>(x, norm1_g, norm1_b, in_proj, ucp);
  k2_conv_proj<<<Bn * Hn, 256, 0, stream>>>(ucp, conv_w, x_proj, ut, dblp);
  k4_scan1<<<Bn * Kn * NCH, 192, 0, stream>>>(ut, dblp, dt_w, dt_b, A_logs,
                                              apb, heb);
  k5_carry<<<12, 256, 0, stream>>>(apb, heb, cin);
  k6_scan2<<<Bn * Kn * NCH, 192, 0, stream>>>(ut, dblp, dt_w, dt_b, A_logs, Ds,
                                              cin, yacc);
  k7_outproj<<<256, 256, 0, stream>>>(yacc, onorm_g, onorm_b, out_proj, x, zt);
  k8_mlp<<<512, 256, 0, stream>>>(zt, norm2_g, norm2_b, fc1_w, fc1_b, fc2_w,
                                  fc2_b, x, out);
}

// Round 3
// 314.151 us; speedup vs baseline: 1.2841x; 1.0404x over previous
//
#include <hip/hip_runtime.h>
#include <math.h>

namespace {

constexpr int Bn = 4, Cn = 96, Hn = 64, Wn = 64, Ln = 4096, Din = 192;
constexpr int Kn = 4, Rn = 6, Dmlp = 384;
constexpr int NCH = 128, CLEN = 32;   // 128 chunks * 32 = L

__device__ __forceinline__ float softplusf_(float x) {
  return fmaxf(x, 0.f) + log1pf(expf(-fabsf(x)));
}
__device__ __forceinline__ float siluf_(float x) { return x / (1.f + expf(-x)); }
__device__ __forceinline__ float geluf_(float x) {
  return 0.5f * x * (1.f + erff(x * 0.7071067811865476f));
}

// ---------------------------------------------------------------------------
// K1: LayerNorm(96) + in_proj (96->192). 32 pixels/block (512 blocks), 256 thr.
// ---------------------------------------------------------------------------
__global__ __launch_bounds__(256) void k1_ln_inproj(
    const float* __restrict__ x, const float* __restrict__ gam,
    const float* __restrict__ bet, const float* __restrict__ W,
    float* __restrict__ ucp) {
  __shared__ float sx[32 * 97];
  const int tid = threadIdx.x;
  const int p0 = blockIdx.x * 32;
  const int b = p0 >> 12, pl0 = p0 & (Ln - 1);

  for (int f = tid; f < 32 * 96; f += 256) {
    int c = f >> 5, pp = f & 31;
    sx[pp * 97 + c] = x[((size_t)b * Cn + c) * Ln + pl0 + pp];
  }
  __syncthreads();
  {
    const int pp = tid >> 3, t8 = tid & 7;   // 8 lanes/pixel, 12 ch each
    float s = 0.f;
    for (int c = t8 * 12; c < t8 * 12 + 12; ++c) s += sx[pp * 97 + c];
    s += __shfl_xor(s, 1, 8); s += __shfl_xor(s, 2, 8); s += __shfl_xor(s, 4, 8);
    float m = s * (1.f / 96.f);
    float v = 0.f;
    for (int c = t8 * 12; c < t8 * 12 + 12; ++c) {
      float t = sx[pp * 97 + c] - m; v += t * t;
    }
    v += __shfl_xor(v, 1, 8); v += __shfl_xor(v, 2, 8); v += __shfl_xor(v, 4, 8);
    float rs = rsqrtf(v * (1.f / 96.f) + 1e-5f);
    for (int c = t8 * 12; c < t8 * 12 + 12; ++c)
      sx[pp * 97 + c] = (sx[pp * 97 + c] - m) * rs * gam[c] + bet[c];
  }
  __syncthreads();

  // GEMM 32px x 192j: pg=tid&7 -> 4 px, q=tid>>3 (0..31) -> 6 j's
  const int pg = tid & 7, q = tid >> 3;
  float acc[4][6];
#pragma unroll
  for (int i = 0; i < 4; ++i)
#pragma unroll
    for (int j = 0; j < 6; ++j) acc[i][j] = 0.f;

  for (int c = 0; c < 96; ++c) {
    float xv[4];
#pragma unroll
    for (int i = 0; i < 4; ++i) xv[i] = sx[(4 * pg + i) * 97 + c];
#pragma unroll
    for (int j = 0; j < 6; ++j) {
      float wv = W[(q * 6 + j) * 96 + c];
#pragma unroll
      for (int i = 0; i < 4; ++i) acc[i][j] = fmaf(xv[i], wv, acc[i][j]);
    }
  }
#pragma unroll
  for (int j = 0; j < 6; ++j) {
    int jj = q * 6 + j;
    float4 v = make_float4(acc[0][j], acc[1][j], acc[2][j], acc[3][j]);
    *reinterpret_cast<float4*>(
        &ucp[((size_t)b * Din + jj) * Ln + pl0 + 4 * pg]) = v;
  }
}

// ---------------------------------------------------------------------------
// K2: depthwise 3x3 conv + SiLU -> ut (B,L,Din) pixel-major
//     + fused x_proj -> dblp (B,L,K,8)
// ---------------------------------------------------------------------------
__global__ __launch_bounds__(256) void k2_conv_proj(
    const float* __restrict__ ucp, const float* __restrict__ cw,
    const float* __restrict__ xw, float* __restrict__ ut,
    float* __restrict__ dblp) {
  __shared__ float su[64 * 193];
  const int tid = threadIdx.x;
  const int bh = blockIdx.x;
  const int b = bh >> 6, h = bh & 63;
  const int w = tid & 63, wg = tid >> 6;

  for (int dd = 0; dd < 48; ++dd) {
    int d = wg * 48 + dd;
    const float* base = &ucp[((size_t)b * Din + d) * Ln];
    float r0 = (h > 0) ? base[(h - 1) * 64 + w] : 0.f;
    float r1 = base[h * 64 + w];
    float r2 = (h < 63) ? base[(h + 1) * 64 + w] : 0.f;
    const float* wt = &cw[d * 9];
    float rl, rr, acc;
    rl = __shfl(r0, (w + 63) & 63); if (w == 0) rl = 0.f;
    rr = __shfl(r0, (w + 1) & 63);  if (w == 63) rr = 0.f;
    acc = rl * wt[0] + r0 * wt[1] + rr * wt[2];
    rl = __shfl(r1, (w + 63) & 63); if (w == 0) rl = 0.f;
    rr = __shfl(r1, (w + 1) & 63);  if (w == 63) rr = 0.f;
    acc += rl * wt[3] + r1 * wt[4] + rr * wt[5];
    rl = __shfl(r2, (w + 63) & 63); if (w == 0) rl = 0.f;
    rr = __shfl(r2, (w + 1) & 63);  if (w == 63) rr = 0.f;
    acc += rl * wt[6] + r2 * wt[7] + rr * wt[8];
    su[w * 193 + d] = siluf_(acc);
  }
  __syncthreads();

  for (int f = tid; f < 64 * Din; f += 256) {
    int pp = f / Din, d = f % Din;
    ut[((size_t)b * Ln + h * 64 + pp) * Din + d] = su[pp * 193 + d];
  }

  const int w2 = tid >> 2, k = tid & 3;
  float a8[8];
#pragma unroll
  for (int j = 0; j < 8; ++j) a8[j] = 0.f;
  for (int d = 0; d < Din; ++d) {
    float uv = su[w2 * 193 + d];
#pragma unroll
    for (int j = 0; j < 8; ++j)
      a8[j] = fmaf(uv, xw[(k * 8 + j) * Din + d], a8[j]);
  }
  size_t off = ((size_t)b * Ln + h * 64 + w2) * 32 + k * 8;
#pragma unroll
  for (int j = 0; j < 8; ++j) dblp[off + j] = a8[j];
}

__device__ __forceinline__ int scan_pixel(int k, int l) {
  if (k == 0) return l;
  if (k == 1) return ((l & 63) << 6) | (l >> 6);
  if (k == 2) return Ln - 1 - l;
  int m2 = Ln - 1 - l;
  return ((m2 & 63) << 6) | (m2 >> 6);
}

// ---------------------------------------------------------------------------
// K4: scan pass 1
// ---------------------------------------------------------------------------
__global__ __launch_bounds__(192) void k4_scan1(
    const float* __restrict__ ut, const float* __restrict__ dblp,
    const float* __restrict__ wdtg, const float* __restrict__ bdtg,
    const float* __restrict__ alog, float* __restrict__ apb,
    float* __restrict__ heb) {
  const int bid = blockIdx.x;
  const int ch = bid & (NCH - 1);
  const int bk = bid / NCH;
  const int b = bk >> 2, k = bk & 3;
  const int d = threadIdx.x;

  float wdt[6];
#pragma unroll
  for (int r = 0; r < 6; ++r) wdt[r] = wdtg[(k * Din + d) * 6 + r];
  const float bdt = bdtg[k * Din + d];
  const float Av = -expf(alog[k * Din + d]);

  const float* utb = &ut[(size_t)b * Ln * Din];
  const float* dbb = &dblp[(size_t)b * Ln * 32 + k * 8];

  float h = 0.f, ap = 1.f;
  for (int i = 0; i < CLEN; ++i) {
    int l = ch * CLEN + i;
    int p = scan_pixel(k, l);
    const float* dl = &dbb[(size_t)p * 32];
    float4 q0 = *reinterpret_cast<const float4*>(dl);
    float4 q1 = *reinterpret_cast<const float4*>(dl + 4);
    float xdt = bdt;
    xdt = fmaf(q0.x, wdt[0], xdt); xdt = fmaf(q0.y, wdt[1], xdt);
    xdt = fmaf(q0.z, wdt[2], xdt); xdt = fmaf(q0.w, wdt[3], xdt);
    xdt = fmaf(q1.x, wdt[4], xdt); xdt = fmaf(q1.y, wdt[5], xdt);
    float dt = softplusf_(xdt);
    float bs = q1.z;
    float u = utb[(size_t)p * Din + d];
    float a = expf(dt * Av);
    float bbv = dt * bs * u;
    h = fmaf(a, h, bbv);
    ap *= a;
  }
  size_t o = ((size_t)bk * NCH + ch) * Din + d;
  apb[o] = ap;
  heb[o] = h;
}

// ---------------------------------------------------------------------------
// K5: scan pass 2 — combine chunk carries
// ---------------------------------------------------------------------------
__global__ __launch_bounds__(256) void k5_carry(
    const float* __restrict__ apb, const float* __restrict__ heb,
    float* __restrict__ cin) {
  int t = blockIdx.x * 256 + threadIdx.x;
  if (t >= Bn * Kn * Din) return;
  int bk = t / Din, d = t % Din;
  float c = 0.f;
  for (int ch = 0; ch < NCH; ++ch) {
    size_t o = ((size_t)bk * NCH + ch) * Din + d;
    cin[o] = c;
    c = fmaf(apb[o], c, heb[o]);
  }
}

// ---------------------------------------------------------------------------
// K6: scan pass 3 — recurrence with carry-in, atomic merge into yacc
// ---------------------------------------------------------------------------
__global__ __launch_bounds__(192) void k6_scan2(
    const float* __restrict__ ut, const float* __restrict__ dblp,
    const float* __restrict__ wdtg, const float* __restrict__ bdtg,
    const float* __restrict__ alog, const float* __restrict__ dsg,
    const float* __restrict__ cin, float* __restrict__ yacc) {
  const int bid = blockIdx.x;
  const int ch = bid & (NCH - 1);
  const int bk = bid / NCH;
  const int b = bk >> 2, k = bk & 3;
  const int d = threadIdx.x;

  float wdt[6];
#pragma unroll
  for (int r = 0; r < 6; ++r) wdt[r] = wdtg[(k * Din + d) * 6 + r];
  const float bdt = bdtg[k * Din + d];
  const float Av = -expf(alog[k * Din + d]);
  const float Dv = dsg[k * Din + d];

  const float* utb = &ut[(size_t)b * Ln * Din];
  const float* dbb = &dblp[(size_t)b * Ln * 32 + k * 8];
  float* yb = &yacc[(size_t)b * Ln * Din];

  float h = cin[((size_t)bk * NCH + ch) * Din + d];
  for (int i = 0; i < CLEN; ++i) {
    int l = ch * CLEN + i;
    int p = scan_pixel(k, l);
    const float* dl = &dbb[(size_t)p * 32];
    float4 q0 = *reinterpret_cast<const float4*>(dl);
    float4 q1 = *reinterpret_cast<const float4*>(dl + 4);
    float xdt = bdt;
    xdt = fmaf(q0.x, wdt[0], xdt); xdt = fmaf(q0.y, wdt[1], xdt);
    xdt = fmaf(q0.z, wdt[2], xdt); xdt = fmaf(q0.w, wdt[3], xdt);
    xdt = fmaf(q1.x, wdt[4], xdt); xdt = fmaf(q1.y, wdt[5], xdt);
    float dt = softplusf_(xdt);
    float bs = q1.z, cs = q1.w;
    float u = utb[(size_t)p * Din + d];
    float a = expf(dt * Av);
    float bbv = dt * bs * u;
    h = fmaf(a, h, bbv);
    float y = h * cs + Dv * u;
    atomicAdd(&yb[(size_t)p * Din + d], y);
  }
}

// ---------------------------------------------------------------------------
// K7: out_norm LN(192) + out_proj (192->96) + residual -> zt (B,L,96).
// ---------------------------------------------------------------------------
__global__ __launch_bounds__(256) void k7_outproj(
    const float* __restrict__ yacc, const float* __restrict__ gam,
    const float* __restrict__ bet, const float* __restrict__ W,
    const float* __restrict__ x, float* __restrict__ zt) {
  __shared__ float sy[64 * 193];
  const int tid = threadIdx.x;
  const int p0 = blockIdx.x * 64;
  const int b = p0 >> 12, pl0 = p0 & (Ln - 1);

  for (int f = tid; f < 64 * Din; f += 256) {
    int pp = f / Din, d = f % Din;
    sy[pp * 193 + d] = yacc[((size_t)p0 + pp) * Din + d];
  }
  __syncthreads();
  {
    const int pp = tid >> 2, t4 = tid & 3;
    float s = 0.f;
    for (int d2 = t4 * 48; d2 < t4 * 48 + 48; ++d2) s += sy[pp * 193 + d2];
    s += __shfl_xor(s, 1, 4); s += __shfl_xor(s, 2, 4);
    float m = s * (1.f / 192.f);
    float v = 0.f;
    for (int d2 = t4 * 48; d2 < t4 * 48 + 48; ++d2) {
      float t = sy[pp * 193 + d2] - m; v += t * t;
    }
    v += __shfl_xor(v, 1, 4); v += __shfl_xor(v, 2, 4);
    float rs = rsqrtf(v * (1.f / 192.f) + 1e-5f);
    for (int d2 = t4 * 48; d2 < t4 * 48 + 48; ++d2)
      sy[pp * 193 + d2] = (sy[pp * 193 + d2] - m) * rs * gam[d2] + bet[d2];
  }
  __syncthreads();

  const int g = tid & 15, q = tid >> 4;  // 4 px x 6 c
  float acc[4][6];
#pragma unroll
  for (int i = 0; i < 4; ++i)
#pragma unroll
    for (int j = 0; j < 6; ++j) acc[i][j] = 0.f;

  for (int d2 = 0; d2 < Din; ++d2) {
    float yv[4];
#pragma unroll
    for (int i = 0; i < 4; ++i) yv[i] = sy[(4 * g + i) * 193 + d2];
#pragma unroll
    for (int j = 0; j < 6; ++j) {
      float wv = W[(q * 6 + j) * Din + d2];
#pragma unroll
      for (int i = 0; i < 4; ++i) acc[i][j] = fmaf(yv[i], wv, acc[i][j]);
    }
  }
  __syncthreads();
  float* sz = sy;
#pragma unroll
  for (int j = 0; j < 6; ++j)
#pragma unroll
    for (int i = 0; i < 4; ++i) sz[(4 * g + i) * 97 + q * 6 + j] = acc[i][j];
  __syncthreads();

  for (int f = tid; f < 64 * 96; f += 256) {
    int pp = f / 96, c = f % 96;
    zt[((size_t)p0 + pp) * 96 + c] =
        sz[pp * 97 + c] + x[((size_t)b * Cn + c) * Ln + pl0 + pp];
  }
}

// ---------------------------------------------------------------------------
// K8: MLP fused, N-split into two 192-wide phases to halve LDS (37.6KB).
// fc1 tile 4px x 6j; fc2 tile 4px x 3c accumulated across phases.
// ---------------------------------------------------------------------------
__global__ __launch_bounds__(256) void k8_mlp(
    const float* __restrict__ zt, const float* __restrict__ g2,
    const float* __restrict__ b2, const float* __restrict__ w1,
    const float* __restrict__ b1f, const float* __restrict__ w2,
    const float* __restrict__ b2f, const float* __restrict__ x,
    float* __restrict__ out) {
  __shared__ float smn[32 * 101];
  __shared__ float sh[32 * 193];
  const int tid = threadIdx.x;
  const int p0 = blockIdx.x * 32;
  const int b = p0 >> 12, pl0 = p0 & (Ln - 1);

  for (int f = tid; f < 32 * 96; f += 256) {
    int pp = f / 96, c = f % 96;
    smn[pp * 101 + c] = zt[((size_t)p0 + pp) * 96 + c];
  }
  __syncthreads();
  {
    const int pp = tid >> 3, t8 = tid & 7;
    float s = 0.f;
    for (int c = t8 * 12; c < t8 * 12 + 12; ++c) s += smn[pp * 101 + c];
    s += __shfl_xor(s, 1, 8); s += __shfl_xor(s, 2, 8); s += __shfl_xor(s, 4, 8);
    float m = s * (1.f / 96.f);
    float v = 0.f;
    for (int c = t8 * 12; c < t8 * 12 + 12; ++c) {
      float t = smn[pp * 101 + c] - m; v += t * t;
    }
    v += __shfl_xor(v, 1, 8); v += __shfl_xor(v, 2, 8); v += __shfl_xor(v, 4, 8);
    float rs = rsqrtf(v * (1.f / 96.f) + 1e-5f);
    for (int c = t8 * 12; c < t8 * 12 + 12; ++c)
      smn[pp * 101 + c] = (smn[pp * 101 + c] - m) * rs * g2[c] + b2[c];
  }
  __syncthreads();

  const int g8 = tid & 7, q = tid >> 3;  // px = 4*g8+i ; fc1: 6 j ; fc2: 3 c
  float a2[4][3];
#pragma unroll
  for (int i = 0; i < 4; ++i)
#pragma unroll
    for (int cc = 0; cc < 3; ++cc) a2[i][cc] = 0.f;

  for (int ph = 0; ph < 2; ++ph) {
    // fc1 for this 192-wide N-half (reads smn only)
    float acc[4][6];
#pragma unroll
    for (int i = 0; i < 4; ++i)
#pragma unroll
      for (int j = 0; j < 6; ++j) acc[i][j] = 0.f;
    for (int c = 0; c < 96; ++c) {
      float mv[4];
#pragma unroll
      for (int i = 0; i < 4; ++i) mv[i] = smn[(4 * g8 + i) * 101 + c];
#pragma unroll
      for (int j = 0; j < 6; ++j) {
        float wv = w1[(size_t)(ph * 192 + q * 6 + j) * 96 + c];
#pragma unroll
        for (int i = 0; i < 4; ++i) acc[i][j] = fmaf(mv[i], wv, acc[i][j]);
      }
    }
    __syncthreads();   // (ph1: ensure all fc2 reads of sh from ph0 are done)
#pragma unroll
    for (int j = 0; j < 6; ++j) {
      int jl = q * 6 + j;
      float bj = b1f[ph * 192 + jl];
#pragma unroll
      for (int i = 0; i < 4; ++i)
        sh[(4 * g8 + i) * 193 + jl] = geluf_(acc[i][j] + bj);
    }
    __syncthreads();
    // fc2 partial over this K-half (reads sh)
    for (int kl = 0; kl < 192; ++kl) {
      float hv[4];
#pragma unroll
      for (int i = 0; i < 4; ++i) hv[i] = sh[(4 * g8 + i) * 193 + kl];
#pragma unroll
      for (int cc = 0; cc < 3; ++cc) {
        float wv = w2[(size_t)(q * 3 + cc) * 384 + ph * 192 + kl];
#pragma unroll
        for (int i = 0; i < 4; ++i) a2[i][cc] = fmaf(hv[i], wv, a2[i][cc]);
      }
    }
  }
  __syncthreads();   // done with smn as LN buffer; reuse for MLP output
#pragma unroll
  for (int cc = 0; cc < 3; ++cc)
#pragma unroll
    for (int i = 0; i < 4; ++i)
      smn[(4 * g8 + i) * 101 + q * 3 + cc] = a2[i][cc] + b2f[q * 3 + cc];
  __syncthreads();

  for (int f = tid; f < 32 * 96; f += 256) {
    int c = f >> 5, pp = f & 31;
    size_t xi = ((size_t)b * Cn + c) * Ln + pl0 + pp;
    out[xi] = x[xi] + zt[((size_t)p0 + pp) * 96 + c] + smn[pp * 101 + c];
  }
}

}  // namespace

extern "C" void kernel_launch(void* const* d_in, const int* in_sizes, int n_in,
                              void* d_out, int out_size, void* d_ws,
                              size_t ws_size, hipStream_t stream) {
  const float* x        = (const float*)d_in[0];
  const float* norm1_g  = (const float*)d_in[1];
  const float* norm1_b  = (const float*)d_in[2];
  const float* in_proj  = (const float*)d_in[3];
  const float* conv_w   = (const float*)d_in[4];
  const float* x_proj   = (const float*)d_in[5];
  const float* dt_w     = (const float*)d_in[6];
  const float* dt_b     = (const float*)d_in[7];
  const float* A_logs   = (const float*)d_in[8];
  const float* Ds       = (const float*)d_in[9];
  const float* onorm_g  = (const float*)d_in[10];
  const float* onorm_b  = (const float*)d_in[11];
  const float* out_proj = (const float*)d_in[12];
  const float* norm2_g  = (const float*)d_in[13];
  const float* norm2_b  = (const float*)d_in[14];
  const float* fc1_w    = (const float*)d_in[15];
  const float* fc1_b    = (const float*)d_in[16];
  const float* fc2_w    = (const float*)d_in[17];
  const float* fc2_b    = (const float*)d_in[18];
  float* out = (float*)d_out;

  float* ws = (float*)d_ws;
  size_t o = 0;
  float* ucp  = ws + o; o += (size_t)Bn * Din * Ln;
  float* ut   = ws + o; o += (size_t)Bn * Ln * Din;
  float* dblp = ws + o; o += (size_t)Bn * Ln * 32;
  float* apb  = ws + o; o += (size_t)Bn * Kn * NCH * Din;
  float* heb  = ws + o; o += (size_t)Bn * Kn * NCH * Din;
  float* cin  = ws + o; o += (size_t)Bn * Kn * NCH * Din;
  float* yacc = ws + o; o += (size_t)Bn * Ln * Din;
  float* zt   = ws + o; o += (size_t)Bn * Ln * Cn;

  hipMemsetAsync(yacc, 0, (size_t)Bn * Ln * Din * sizeof(float), stream);

  k1_ln_inproj<<<512, 256, 0, stream>>>(x, norm1_g, norm1_b, in_proj, ucp);
  k2_conv_proj<<<Bn * Hn, 256, 0, stream>>>(ucp, conv_w, x_proj, ut, dblp);
  k4_scan1<<<Bn * Kn * NCH, 192, 0, stream>>>(ut, dblp, dt_w, dt_b, A_logs,
                                              apb, heb);
  k5_carry<<<12, 256, 0, stream>>>(apb, heb, cin);
  k6_scan2<<<Bn * Kn * NCH, 192, 0, stream>>>(ut, dblp, dt_w, dt_b, A_logs, Ds,
                                              cin, yacc);
  k7_outproj<<<256, 256, 0, stream>>>(yacc, onorm_g, onorm_b, out_proj, x, zt);
  k8_mlp<<<512, 256, 0, stream>>>(zt, norm2_g, norm2_b, fc1_w, fc1_b, fc2_w,
                                  fc2_b, x, out);
}